// Round 2
// baseline (179.206 us; speedup 1.0000x reference)
//
#include <hip/hip_runtime.h>
#include <hip/hip_cooperative_groups.h>

namespace cg = cooperative_groups;

#define Bv 16
#define Cv 64
#define Sv 2048
#define NSEG 32           // pli sample-groups per batch (64 samples each)
#define SSEG 64           // samples per pli group
#define ROWS 68           // pli LDS row stride in words (64 ch + 4 pad)
#define NTILE 144         // triangle tiles: dq in 0..8 x qi in 0..15

// Forward DIF butterfly: u' = u+v ; v' = (u-v)*w
__device__ __forceinline__ void bf_f(float2& u, float2& v, const float2 w) {
    const float dr = u.x - v.x, di = u.y - v.y;
    u.x += v.x; u.y += v.y;
    v.x = dr * w.x - di * w.y;
    v.y = dr * w.y + di * w.x;
}
// Inverse DIT butterfly: v' = v*conj(w) ; u' = u+v' ; l' = u-v'
__device__ __forceinline__ void bf_i(float2& u, float2& v, const float2 w) {
    const float vr = v.x * w.x + v.y * w.y;
    const float vi = v.y * w.x - v.x * w.y;
    v.x = u.x - vr; v.y = u.y - vi;
    u.x += vr; u.y += vi;
}
__device__ __forceinline__ float2 csq(const float2 a) {
    return make_float2(a.x * a.x - a.y * a.y, 2.0f * a.x * a.y);
}
__device__ __forceinline__ float2 cm1(const float2 a) {   // a * e^{-i pi/4}
    const float cq = 0.70710678118654752f;
    return make_float2(cq * (a.x + a.y), cq * (a.y - a.x));
}
__device__ __forceinline__ float2 cmi(const float2 a) {   // a * e^{-i pi/2}
    return make_float2(a.y, -a.x);
}
// Bank-conflict-breaking storage map for the FFT scratch: n -> n + n/8.
__device__ __forceinline__ int pad(int n) { return n + (n >> 3); }

// ---------------------------------------------------------------------------
// Single cooperative kernel, 512 blocks x 256 threads, 2 blocks/CU:
//   phase 0: paired-channel Hilbert -> 32-bit fixed-point phase u   (512 blk)
//   grid.sync()
//   phase 1: PLI negative-sign counts, 64-sample groups, u8 partials (512 blk)
//   grid.sync()
//   phase 2: reduce partials -> PLI                                  (65536 thr)
// Rationale: R1 showed kernel bodies run at modeled speed (~11 us total);
// the bulk of dur_us is inter-dispatch overhead. One launch removes it.
// ---------------------------------------------------------------------------
__global__ __launch_bounds__(256, 2) void pli_fused(const float* __restrict__ x,
                                                    unsigned int* __restrict__ u,
                                                    unsigned int* __restrict__ part,
                                                    float* __restrict__ out) {
    // Time-shared LDS: FFT scratch (18432 B) / count tile (17408 B)
    __shared__ __align__(16) unsigned char shraw[(Sv + Sv / 8) * sizeof(float2)];
    float2* const zz = (float2*)shraw;
    unsigned int* const uL = (unsigned int*)shraw;
    const int t = threadIdx.x;
    cg::grid_group grid = cg::this_grid();

    // ===================== phase 0: Hilbert + phase quantize =====================
    {
        const int c0 = blockIdx.x * 2;
        const float* x0 = x + (size_t)c0 * Sv;
        const float* x1 = x0 + Sv;

        const float PI = 3.14159265358979323846f;
        float2 bA4, bB4, bC2;
        sincosf(-PI * (float)t * (1.0f / 1024.0f), &bA4.y, &bA4.x);
        sincosf(-PI * (float)(t & 31) * (1.0f / 128.0f), &bB4.y, &bB4.x);
        sincosf(-PI * (float)(t & 7) * (1.0f / 16.0f), &bC2.y, &bC2.x);
        const float2 bA2 = csq(bA4), bA1 = csq(bA2);
        const float2 bB2 = csq(bB4), bB1 = csq(bB2);
        const float2 bC1 = csq(bC2);

        // Keep x in registers across the FFT so the epilogue needs no re-load.
        float xa[8], xb[8];
        float2 z[8];
        #pragma unroll
        for (int k = 0; k < 8; ++k) {
            xa[k] = x0[t + 256 * k];
            xb[k] = x1[t + 256 * k];
            z[k] = make_float2(xa[k], xb[k]);
        }

        // ---- fwd halves 1024,512,256 (stride 256) ----
        {
            const float2 w1 = cm1(bA4);
            bf_f(z[0], z[4], bA4);      bf_f(z[1], z[5], w1);
            bf_f(z[2], z[6], cmi(bA4)); bf_f(z[3], z[7], cmi(w1));
            const float2 wB = cmi(bA2);
            bf_f(z[0], z[2], bA2); bf_f(z[1], z[3], wB);
            bf_f(z[4], z[6], bA2); bf_f(z[5], z[7], wB);
            bf_f(z[0], z[1], bA1); bf_f(z[2], z[3], bA1);
            bf_f(z[4], z[5], bA1); bf_f(z[6], z[7], bA1);
        }
        #pragma unroll
        for (int k = 0; k < 8; ++k) zz[pad(t + 256 * k)] = z[k];
        __syncthreads();

        // ---- fwd halves 128,64,32 (stride 32) ----
        {
            const int r = t & 31, base = (t >> 5) * 256 + r;
            #pragma unroll
            for (int k = 0; k < 8; ++k) z[k] = zz[pad(base + 32 * k)];
            const float2 w1 = cm1(bB4);
            bf_f(z[0], z[4], bB4);      bf_f(z[1], z[5], w1);
            bf_f(z[2], z[6], cmi(bB4)); bf_f(z[3], z[7], cmi(w1));
            const float2 wB = cmi(bB2);
            bf_f(z[0], z[2], bB2); bf_f(z[1], z[3], wB);
            bf_f(z[4], z[6], bB2); bf_f(z[5], z[7], wB);
            bf_f(z[0], z[1], bB1); bf_f(z[2], z[3], bB1);
            bf_f(z[4], z[5], bB1); bf_f(z[6], z[7], bB1);
            #pragma unroll
            for (int k = 0; k < 8; ++k) zz[pad(base + 32 * k)] = z[k];
        }
        __syncthreads();

        // ---- fwd halves 16,8 (stride 8; two 4-sets) ----
        {
            const int r = t & 7, base0 = (t >> 3) * 32 + r, base1 = base0 + 1024;
            #pragma unroll
            for (int k = 0; k < 4; ++k) {
                z[k] = zz[pad(base0 + 8 * k)];
                z[4 + k] = zz[pad(base1 + 8 * k)];
            }
            const float2 wB = cmi(bC2);
            bf_f(z[0], z[2], bC2); bf_f(z[1], z[3], wB);
            bf_f(z[4], z[6], bC2); bf_f(z[5], z[7], wB);
            bf_f(z[0], z[1], bC1); bf_f(z[2], z[3], bC1);
            bf_f(z[4], z[5], bC1); bf_f(z[6], z[7], bC1);
            #pragma unroll
            for (int k = 0; k < 4; ++k) {
                zz[pad(base0 + 8 * k)] = z[k];
                zz[pad(base1 + 8 * k)] = z[4 + k];
            }
        }
        __syncthreads();

        // ---- fused: fwd 4,2,1 ; Hilbert filter * 1/N ; inv 1,2,4 ----
        {
            const int base = 8 * t;
            #pragma unroll
            for (int k = 0; k < 8; ++k) z[k] = zz[pad(base + k)];
            const float cq = 0.70710678118654752f;
            const float2 W1  = make_float2(1.0f, 0.0f);
            const float2 W41 = make_float2(cq, -cq);
            const float2 W42 = make_float2(0.0f, -1.0f);
            const float2 W43 = make_float2(-cq, -cq);
            bf_f(z[0], z[4], W1);  bf_f(z[1], z[5], W41);
            bf_f(z[2], z[6], W42); bf_f(z[3], z[7], W43);
            bf_f(z[0], z[2], W1); bf_f(z[1], z[3], W42);
            bf_f(z[4], z[6], W1); bf_f(z[5], z[7], W42);
            bf_f(z[0], z[1], W1); bf_f(z[2], z[3], W1);
            bf_f(z[4], z[5], W1); bf_f(z[6], z[7], W1);
            const float inv = 1.0f / (float)Sv;
            #pragma unroll
            for (int k = 0; k < 8; ++k) {
                const int kk = (int)(__brev((unsigned)(base + k)) >> 21);   // logical index!
                const float m = (kk == 0 || kk == Sv / 2) ? inv : (kk < Sv / 2 ? 2.0f * inv : 0.0f);
                z[k].x *= m; z[k].y *= m;
            }
            bf_i(z[0], z[1], W1); bf_i(z[2], z[3], W1);
            bf_i(z[4], z[5], W1); bf_i(z[6], z[7], W1);
            bf_i(z[0], z[2], W1); bf_i(z[1], z[3], W42);
            bf_i(z[4], z[6], W1); bf_i(z[5], z[7], W42);
            bf_i(z[0], z[4], W1);  bf_i(z[1], z[5], W41);
            bf_i(z[2], z[6], W42); bf_i(z[3], z[7], W43);
            #pragma unroll
            for (int k = 0; k < 8; ++k) zz[pad(base + k)] = z[k];
        }
        __syncthreads();

        // ---- inv halves 8,16 (stride 8; two 4-sets) ----
        {
            const int r = t & 7, base0 = (t >> 3) * 32 + r, base1 = base0 + 1024;
            #pragma unroll
            for (int k = 0; k < 4; ++k) {
                z[k] = zz[pad(base0 + 8 * k)];
                z[4 + k] = zz[pad(base1 + 8 * k)];
            }
            bf_i(z[0], z[1], bC1); bf_i(z[2], z[3], bC1);
            bf_i(z[4], z[5], bC1); bf_i(z[6], z[7], bC1);
            const float2 wB = cmi(bC2);
            bf_i(z[0], z[2], bC2); bf_i(z[1], z[3], wB);
            bf_i(z[4], z[6], bC2); bf_i(z[5], z[7], wB);
            #pragma unroll
            for (int k = 0; k < 4; ++k) {
                zz[pad(base0 + 8 * k)] = z[k];
                zz[pad(base1 + 8 * k)] = z[4 + k];
            }
        }
        __syncthreads();

        // ---- inv halves 32,64,128 (stride 32) ----
        {
            const int r = t & 31, base = (t >> 5) * 256 + r;
            #pragma unroll
            for (int k = 0; k < 8; ++k) z[k] = zz[pad(base + 32 * k)];
            bf_i(z[0], z[1], bB1); bf_i(z[2], z[3], bB1);
            bf_i(z[4], z[5], bB1); bf_i(z[6], z[7], bB1);
            const float2 wB = cmi(bB2);
            bf_i(z[0], z[2], bB2); bf_i(z[1], z[3], wB);
            bf_i(z[4], z[6], bB2); bf_i(z[5], z[7], wB);
            const float2 w1 = cm1(bB4);
            bf_i(z[0], z[4], bB4);      bf_i(z[1], z[5], w1);
            bf_i(z[2], z[6], cmi(bB4)); bf_i(z[3], z[7], cmi(w1));
            #pragma unroll
            for (int k = 0; k < 8; ++k) zz[pad(base + 32 * k)] = z[k];
        }
        __syncthreads();

        // ---- inv halves 256,512,1024 (stride 256) + fused phase-quantize write ----
        {
            #pragma unroll
            for (int k = 0; k < 8; ++k) z[k] = zz[pad(t + 256 * k)];
            bf_i(z[0], z[1], bA1); bf_i(z[2], z[3], bA1);
            bf_i(z[4], z[5], bA1); bf_i(z[6], z[7], bA1);
            const float2 wB = cmi(bA2);
            bf_i(z[0], z[2], bA2); bf_i(z[1], z[3], wB);
            bf_i(z[4], z[6], bA2); bf_i(z[5], z[7], wB);
            const float2 w1 = cm1(bA4);
            bf_i(z[0], z[4], bA4);      bf_i(z[1], z[5], w1);
            bf_i(z[2], z[6], cmi(bA4)); bf_i(z[3], z[7], cmi(w1));
            unsigned int* u0 = u + (size_t)c0 * Sv;
            unsigned int* u1 = u0 + Sv;
            const float SC = 683565275.576f;   // 2^31 / pi ; mod 2^32 == mod 2*pi
            #pragma unroll
            for (int k = 0; k < 8; ++k) {
                const int n = t + 256 * k;
                const float ha = z[k].y - xb[k];   // H(x_a) = Im(w) - x_b
                const float hb = xa[k] - z[k].x;   // H(x_b) = x_a - Re(w)
                u0[n] = (unsigned int)__float2int_rz(atan2f(ha, xa[k]) * SC);
                u1[n] = (unsigned int)__float2int_rz(atan2f(hb, xb[k]) * SC);
            }
        }
    }

    grid.sync();

    // ===================== phase 1: PLI negative-sign counts =====================
    // 512 blocks: b = blk>>5, group g = blk&31 covers 64 consecutive samples.
    // Counts <= 64 fit u8; part = [b][g][144 tiles][16 u8] = 1.18 MB.
    {
        const int blk = blockIdx.x;
        const int g = blk & (NSEG - 1);
        const int b = blk >> 5;
        const unsigned int* ub = u + (size_t)b * Cv * Sv + g * SSEG;

        #pragma unroll
        for (int it = 0; it < 16; ++it) {
            const int e = t + 256 * it;
            const int ch = e >> 6;
            const int s = e & (SSEG - 1);
            uL[s * ROWS + ch] = ub[(size_t)ch * Sv + s];
        }
        __syncthreads();

        if (t < NTILE) {
            const int qi = t & 15;
            const int dq = t >> 4;                  // 0..8
            const int i0 = qi * 4;
            const int j0 = ((qi + dq) & 15) * 4;
            int neg[4][4] = {};

            #pragma unroll 4
            for (int s = 0; s < SSEG; ++s) {
                const uint4 ui = *(const uint4*)&uL[s * ROWS + i0];
                const uint4 uj = *(const uint4*)&uL[s * ROWS + j0];
                const unsigned int uia[4] = {ui.x, ui.y, ui.z, ui.w};
                const unsigned int uja[4] = {uj.x, uj.y, uj.z, uj.w};
                #pragma unroll
                for (int a = 0; a < 4; ++a) {
                    #pragma unroll
                    for (int c = 0; c < 4; ++c) {
                        // wrapped phase diff negative <=> top bit of (uia-uja)
                        neg[a][c] += (int)((uia[a] - uja[c]) >> 31);
                    }
                }
            }

            unsigned int* Pb = part + ((size_t)blk * NTILE + t) * 4;
            unsigned int pk[4];
            #pragma unroll
            for (int a = 0; a < 4; ++a)
                pk[a] = (unsigned)neg[a][0] | ((unsigned)neg[a][1] << 8)
                      | ((unsigned)neg[a][2] << 16) | ((unsigned)neg[a][3] << 24);
            *(uint4*)Pb = make_uint4(pk[0], pk[1], pk[2], pk[3]);
        }
    }

    grid.sync();

    // ===================== phase 2: reduce partials -> PLI =====================
    {
        const int idx = blockIdx.x * 256 + t;      // 131072 threads, 65536 outputs
        if (idx < Bv * Cv * Cv) {
            const unsigned char* pc = (const unsigned char*)part;
            const int b = idx >> 12;
            const int ij = idx & 4095;
            const int i = ij >> 6, j = ij & 63;
            const int qi = i >> 2, a = i & 3;
            const int qj = j >> 2, c = j & 3;
            const int gg = (qj - qi) & 15;
            int byteoff;
            if (gg <= 8) byteoff = (gg * 16 + qi) * 16 + a * 4 + c;
            else         byteoff = ((16 - gg) * 16 + qj) * 16 + c * 4 + a;
            const unsigned char* p = pc + (size_t)b * NSEG * (NTILE * 16) + byteoff;
            int negsum = 0;
            #pragma unroll 8
            for (int s = 0; s < NSEG; ++s)
                negsum += (int)p[s * (NTILE * 16)];
            out[idx] = (i == j) ? 0.0f
                                : fabsf((float)Sv - 2.0f * (float)negsum) * (1.0f / (float)Sv);
        }
    }
}

extern "C" void kernel_launch(void* const* d_in, const int* in_sizes, int n_in,
                              void* d_out, int out_size, void* d_ws, size_t ws_size,
                              hipStream_t stream) {
    const float* x = (const float*)d_in[0];            // [B, C, S] fp32
    unsigned int* u = (unsigned int*)d_ws;             // [B, C, S] u32 phase (8 MB)
    unsigned int* part = (unsigned int*)((char*)d_ws + (size_t)Bv * Cv * Sv * sizeof(unsigned int));
    float* out = (float*)d_out;                        // [B, C, C] fp32

    void* args[] = { (void*)&x, (void*)&u, (void*)&part, (void*)&out };
    hipLaunchCooperativeKernel((void*)pli_fused, dim3(Bv * Cv / 2), dim3(256),
                               args, 0, stream);
}

// Round 3
// 119.877 us; speedup vs baseline: 1.4949x; 1.4949x over previous
//
#include <hip/hip_runtime.h>

#define Bv 16
#define Cv 64
#define Sv 2048
#define NSEG 32           // pli sample-groups per batch (64 samples each)
#define SSEG 64           // samples per pli group
#define ROWS 68           // pli LDS row stride in words (64 ch + 4 pad)
#define NTILE 144         // triangle tiles: dq in 0..8 x qi in 0..15
#define MAGICF 0x4F1BBCDCu   // flag value; workspace poison-fill resets flags each iter

// Forward DIF butterfly: u' = u+v ; v' = (u-v)*w
__device__ __forceinline__ void bf_f(float2& u, float2& v, const float2 w) {
    const float dr = u.x - v.x, di = u.y - v.y;
    u.x += v.x; u.y += v.y;
    v.x = dr * w.x - di * w.y;
    v.y = dr * w.y + di * w.x;
}
// Inverse DIT butterfly: v' = v*conj(w) ; u' = u+v' ; l' = u-v'
__device__ __forceinline__ void bf_i(float2& u, float2& v, const float2 w) {
    const float vr = v.x * w.x + v.y * w.y;
    const float vi = v.y * w.x - v.x * w.y;
    v.x = u.x - vr; v.y = u.y - vi;
    u.x += vr; u.y += vi;
}
__device__ __forceinline__ float2 csq(const float2 a) {
    return make_float2(a.x * a.x - a.y * a.y, 2.0f * a.x * a.y);
}
__device__ __forceinline__ float2 cm1(const float2 a) {   // a * e^{-i pi/4}
    const float cq = 0.70710678118654752f;
    return make_float2(cq * (a.x + a.y), cq * (a.y - a.x));
}
__device__ __forceinline__ float2 cmi(const float2 a) {   // a * e^{-i pi/2}
    return make_float2(a.y, -a.x);
}
// Bank-conflict-breaking storage map for the FFT scratch: n -> n + n/8.
__device__ __forceinline__ int pad(int n) { return n + (n >> 3); }

// Agent-scope (cross-XCD-safe, LLC-direct) accessors. u and part have zero
// per-element reuse, so bypassing the per-XCD L2 costs nothing.
__device__ __forceinline__ unsigned int ld_agent(const unsigned int* p) {
    return __hip_atomic_load((unsigned int*)p, __ATOMIC_RELAXED, __HIP_MEMORY_SCOPE_AGENT);
}
__device__ __forceinline__ void st_agent(unsigned int* p, unsigned int v) {
    __hip_atomic_store(p, v, __ATOMIC_RELAXED, __HIP_MEMORY_SCOPE_AGENT);
}

// ---------------------------------------------------------------------------
// Single NON-cooperative kernel, 512 blocks x 256 threads (2 blocks/CU, all
// resident -- proven by R2's cooperative launch at identical geometry):
//   phase 0: block blk -> Hilbert for channels 2blk,2blk+1 -> u32 phases
//            set flags1[blk]; wave0 polls the 32 flags1 of its batch
//   phase 1: block (b,g) -> PLI sign counts for 64-sample group g -> partials
//            set flags2[blk]
//   phase 2: block (b,g==0) polls batch's flags2, reduces partials -> out
// Per-batch rendezvous (32 blocks) with relaxed agent-scope flag polling --
// none of CG grid.sync()'s global barrier + cache-maintenance storm (R2: ~50us
// per sync). Bounded spins guarantee termination.
// ---------------------------------------------------------------------------
__global__ __launch_bounds__(256, 2) void pli_one(const float* __restrict__ x,
                                                  unsigned int* __restrict__ u,
                                                  unsigned int* __restrict__ part,
                                                  unsigned int* __restrict__ flags1,
                                                  unsigned int* __restrict__ flags2,
                                                  float* __restrict__ out) {
    // Time-shared LDS: FFT scratch (18432 B) / count tile (17408 B)
    __shared__ __align__(16) unsigned char shraw[(Sv + Sv / 8) * sizeof(float2)];
    float2* const zz = (float2*)shraw;
    unsigned int* const uL = (unsigned int*)shraw;
    const int t = threadIdx.x;
    const int blk = blockIdx.x;
    const int b = blk >> 5;          // batch (same for hilbert + count roles)
    const int g = blk & (NSEG - 1);  // sample group for count role

    // ===================== phase 0: Hilbert + phase quantize =====================
    {
        const int c0 = blk * 2;
        const float* x0 = x + (size_t)c0 * Sv;
        const float* x1 = x0 + Sv;

        const float PI = 3.14159265358979323846f;
        float2 bA4, bB4, bC2;
        sincosf(-PI * (float)t * (1.0f / 1024.0f), &bA4.y, &bA4.x);
        sincosf(-PI * (float)(t & 31) * (1.0f / 128.0f), &bB4.y, &bB4.x);
        sincosf(-PI * (float)(t & 7) * (1.0f / 16.0f), &bC2.y, &bC2.x);
        const float2 bA2 = csq(bA4), bA1 = csq(bA2);
        const float2 bB2 = csq(bB4), bB1 = csq(bB2);
        const float2 bC1 = csq(bC2);

        float xa[8], xb[8];
        float2 z[8];
        #pragma unroll
        for (int k = 0; k < 8; ++k) {
            xa[k] = x0[t + 256 * k];
            xb[k] = x1[t + 256 * k];
            z[k] = make_float2(xa[k], xb[k]);
        }

        // ---- fwd halves 1024,512,256 (stride 256) ----
        {
            const float2 w1 = cm1(bA4);
            bf_f(z[0], z[4], bA4);      bf_f(z[1], z[5], w1);
            bf_f(z[2], z[6], cmi(bA4)); bf_f(z[3], z[7], cmi(w1));
            const float2 wB = cmi(bA2);
            bf_f(z[0], z[2], bA2); bf_f(z[1], z[3], wB);
            bf_f(z[4], z[6], bA2); bf_f(z[5], z[7], wB);
            bf_f(z[0], z[1], bA1); bf_f(z[2], z[3], bA1);
            bf_f(z[4], z[5], bA1); bf_f(z[6], z[7], bA1);
        }
        #pragma unroll
        for (int k = 0; k < 8; ++k) zz[pad(t + 256 * k)] = z[k];
        __syncthreads();

        // ---- fwd halves 128,64,32 (stride 32) ----
        {
            const int r = t & 31, base = (t >> 5) * 256 + r;
            #pragma unroll
            for (int k = 0; k < 8; ++k) z[k] = zz[pad(base + 32 * k)];
            const float2 w1 = cm1(bB4);
            bf_f(z[0], z[4], bB4);      bf_f(z[1], z[5], w1);
            bf_f(z[2], z[6], cmi(bB4)); bf_f(z[3], z[7], cmi(w1));
            const float2 wB = cmi(bB2);
            bf_f(z[0], z[2], bB2); bf_f(z[1], z[3], wB);
            bf_f(z[4], z[6], bB2); bf_f(z[5], z[7], wB);
            bf_f(z[0], z[1], bB1); bf_f(z[2], z[3], bB1);
            bf_f(z[4], z[5], bB1); bf_f(z[6], z[7], bB1);
            #pragma unroll
            for (int k = 0; k < 8; ++k) zz[pad(base + 32 * k)] = z[k];
        }
        __syncthreads();

        // ---- fwd halves 16,8 (stride 8; two 4-sets) ----
        {
            const int r = t & 7, base0 = (t >> 3) * 32 + r, base1 = base0 + 1024;
            #pragma unroll
            for (int k = 0; k < 4; ++k) {
                z[k] = zz[pad(base0 + 8 * k)];
                z[4 + k] = zz[pad(base1 + 8 * k)];
            }
            const float2 wB = cmi(bC2);
            bf_f(z[0], z[2], bC2); bf_f(z[1], z[3], wB);
            bf_f(z[4], z[6], bC2); bf_f(z[5], z[7], wB);
            bf_f(z[0], z[1], bC1); bf_f(z[2], z[3], bC1);
            bf_f(z[4], z[5], bC1); bf_f(z[6], z[7], bC1);
            #pragma unroll
            for (int k = 0; k < 4; ++k) {
                zz[pad(base0 + 8 * k)] = z[k];
                zz[pad(base1 + 8 * k)] = z[4 + k];
            }
        }
        __syncthreads();

        // ---- fused: fwd 4,2,1 ; Hilbert filter * 1/N ; inv 1,2,4 ----
        {
            const int base = 8 * t;
            #pragma unroll
            for (int k = 0; k < 8; ++k) z[k] = zz[pad(base + k)];
            const float cq = 0.70710678118654752f;
            const float2 W1  = make_float2(1.0f, 0.0f);
            const float2 W41 = make_float2(cq, -cq);
            const float2 W42 = make_float2(0.0f, -1.0f);
            const float2 W43 = make_float2(-cq, -cq);
            bf_f(z[0], z[4], W1);  bf_f(z[1], z[5], W41);
            bf_f(z[2], z[6], W42); bf_f(z[3], z[7], W43);
            bf_f(z[0], z[2], W1); bf_f(z[1], z[3], W42);
            bf_f(z[4], z[6], W1); bf_f(z[5], z[7], W42);
            bf_f(z[0], z[1], W1); bf_f(z[2], z[3], W1);
            bf_f(z[4], z[5], W1); bf_f(z[6], z[7], W1);
            const float inv = 1.0f / (float)Sv;
            #pragma unroll
            for (int k = 0; k < 8; ++k) {
                const int kk = (int)(__brev((unsigned)(base + k)) >> 21);   // logical index!
                const float m = (kk == 0 || kk == Sv / 2) ? inv : (kk < Sv / 2 ? 2.0f * inv : 0.0f);
                z[k].x *= m; z[k].y *= m;
            }
            bf_i(z[0], z[1], W1); bf_i(z[2], z[3], W1);
            bf_i(z[4], z[5], W1); bf_i(z[6], z[7], W1);
            bf_i(z[0], z[2], W1); bf_i(z[1], z[3], W42);
            bf_i(z[4], z[6], W1); bf_i(z[5], z[7], W42);
            bf_i(z[0], z[4], W1);  bf_i(z[1], z[5], W41);
            bf_i(z[2], z[6], W42); bf_i(z[3], z[7], W43);
            #pragma unroll
            for (int k = 0; k < 8; ++k) zz[pad(base + k)] = z[k];
        }
        __syncthreads();

        // ---- inv halves 8,16 (stride 8; two 4-sets) ----
        {
            const int r = t & 7, base0 = (t >> 3) * 32 + r, base1 = base0 + 1024;
            #pragma unroll
            for (int k = 0; k < 4; ++k) {
                z[k] = zz[pad(base0 + 8 * k)];
                z[4 + k] = zz[pad(base1 + 8 * k)];
            }
            bf_i(z[0], z[1], bC1); bf_i(z[2], z[3], bC1);
            bf_i(z[4], z[5], bC1); bf_i(z[6], z[7], bC1);
            const float2 wB = cmi(bC2);
            bf_i(z[0], z[2], bC2); bf_i(z[1], z[3], wB);
            bf_i(z[4], z[6], bC2); bf_i(z[5], z[7], wB);
            #pragma unroll
            for (int k = 0; k < 4; ++k) {
                zz[pad(base0 + 8 * k)] = z[k];
                zz[pad(base1 + 8 * k)] = z[4 + k];
            }
        }
        __syncthreads();

        // ---- inv halves 32,64,128 (stride 32) ----
        {
            const int r = t & 31, base = (t >> 5) * 256 + r;
            #pragma unroll
            for (int k = 0; k < 8; ++k) z[k] = zz[pad(base + 32 * k)];
            bf_i(z[0], z[1], bB1); bf_i(z[2], z[3], bB1);
            bf_i(z[4], z[5], bB1); bf_i(z[6], z[7], bB1);
            const float2 wB = cmi(bB2);
            bf_i(z[0], z[2], bB2); bf_i(z[1], z[3], wB);
            bf_i(z[4], z[6], bB2); bf_i(z[5], z[7], wB);
            const float2 w1 = cm1(bB4);
            bf_i(z[0], z[4], bB4);      bf_i(z[1], z[5], w1);
            bf_i(z[2], z[6], cmi(bB4)); bf_i(z[3], z[7], cmi(w1));
            #pragma unroll
            for (int k = 0; k < 8; ++k) zz[pad(base + 32 * k)] = z[k];
        }
        __syncthreads();

        // ---- inv halves 256,512,1024 (stride 256) + phase-quantize (agent st) ----
        {
            #pragma unroll
            for (int k = 0; k < 8; ++k) z[k] = zz[pad(t + 256 * k)];
            bf_i(z[0], z[1], bA1); bf_i(z[2], z[3], bA1);
            bf_i(z[4], z[5], bA1); bf_i(z[6], z[7], bA1);
            const float2 wB = cmi(bA2);
            bf_i(z[0], z[2], bA2); bf_i(z[1], z[3], wB);
            bf_i(z[4], z[6], bA2); bf_i(z[5], z[7], wB);
            const float2 w1 = cm1(bA4);
            bf_i(z[0], z[4], bA4);      bf_i(z[1], z[5], w1);
            bf_i(z[2], z[6], cmi(bA4)); bf_i(z[3], z[7], cmi(w1));
            unsigned int* u0 = u + (size_t)c0 * Sv;
            unsigned int* u1 = u0 + Sv;
            const float SC = 683565275.576f;   // 2^31 / pi ; mod 2^32 == mod 2*pi
            #pragma unroll
            for (int k = 0; k < 8; ++k) {
                const int n = t + 256 * k;
                const float ha = z[k].y - xb[k];   // H(x_a) = Im(w) - x_b
                const float hb = xa[k] - z[k].x;   // H(x_b) = x_a - Re(w)
                st_agent(&u0[n], (unsigned int)__float2int_rz(atan2f(ha, xa[k]) * SC));
                st_agent(&u1[n], (unsigned int)__float2int_rz(atan2f(hb, xb[k]) * SC));
            }
        }
    }

    // Publish phase-0 completion; all waves drained (syncthreads => vmcnt(0)).
    __syncthreads();
    if (t == 0)
        __hip_atomic_store(&flags1[blk], MAGICF, __ATOMIC_RELEASE, __HIP_MEMORY_SCOPE_AGENT);

    // Rendezvous: wait for all 32 hilbert blocks of batch b (wave-parallel poll).
    if (t < 32) {
        const unsigned int* f = flags1 + b * 32;
        int guard = 0;
        while (ld_agent(&f[t]) != MAGICF && guard < (1 << 20)) {
            ++guard;
            __builtin_amdgcn_s_sleep(2);
        }
    }
    __syncthreads();

    // ===================== phase 1: PLI negative-sign counts =====================
    {
        const unsigned int* ub = u + (size_t)b * Cv * Sv + g * SSEG;

        #pragma unroll
        for (int it = 0; it < 16; ++it) {
            const int e = t + 256 * it;
            const int ch = e >> 6;
            const int s = e & (SSEG - 1);
            uL[s * ROWS + ch] = ld_agent(&ub[(size_t)ch * Sv + s]);
        }
        __syncthreads();

        if (t < NTILE) {
            const int qi = t & 15;
            const int dq = t >> 4;                  // 0..8
            const int i0 = qi * 4;
            const int j0 = ((qi + dq) & 15) * 4;
            int neg[4][4] = {};

            #pragma unroll 4
            for (int s = 0; s < SSEG; ++s) {
                const uint4 ui = *(const uint4*)&uL[s * ROWS + i0];
                const uint4 uj = *(const uint4*)&uL[s * ROWS + j0];
                const unsigned int uia[4] = {ui.x, ui.y, ui.z, ui.w};
                const unsigned int uja[4] = {uj.x, uj.y, uj.z, uj.w};
                #pragma unroll
                for (int a = 0; a < 4; ++a) {
                    #pragma unroll
                    for (int c = 0; c < 4; ++c) {
                        // wrapped phase diff negative <=> top bit of (uia-uja)
                        neg[a][c] += (int)((uia[a] - uja[c]) >> 31);
                    }
                }
            }

            unsigned int* Pb = part + ((size_t)blk * NTILE + t) * 4;
            #pragma unroll
            for (int a = 0; a < 4; ++a) {
                const unsigned int pk = (unsigned)neg[a][0] | ((unsigned)neg[a][1] << 8)
                                      | ((unsigned)neg[a][2] << 16) | ((unsigned)neg[a][3] << 24);
                st_agent(&Pb[a], pk);
            }
        }
    }

    __syncthreads();
    if (t == 0)
        __hip_atomic_store(&flags2[blk], MAGICF, __ATOMIC_RELEASE, __HIP_MEMORY_SCOPE_AGENT);

    // ===================== phase 2: finalize (one block per batch) =====================
    if (g != 0) return;

    if (t < 32) {
        const unsigned int* f = flags2 + b * 32;
        int guard = 0;
        while (ld_agent(&f[t]) != MAGICF && guard < (1 << 20)) {
            ++guard;
            __builtin_amdgcn_s_sleep(2);
        }
    }
    __syncthreads();

    {
        const unsigned int* pw = part + (size_t)b * (NSEG * NTILE * 4);
        #pragma unroll
        for (int q = 0; q < 16; ++q) {
            const int ij = q * 256 + t;            // 4096 outputs for this batch
            const int i = ij >> 6, j = ij & 63;
            const int qi = i >> 2, a = i & 3;
            const int qj = j >> 2, c = j & 3;
            const int gg = (qj - qi) & 15;
            int tile, wsel, bsel;
            if (gg <= 8) { tile = gg * 16 + qi;        wsel = a; bsel = c; }
            else         { tile = (16 - gg) * 16 + qj; wsel = c; bsel = a; }
            const unsigned int* pp = pw + tile * 4 + wsel;
            int negsum = 0;
            #pragma unroll 8
            for (int s = 0; s < NSEG; ++s)
                negsum += (int)((ld_agent(&pp[s * (NTILE * 4)]) >> (8 * bsel)) & 255u);
            out[b * (Cv * Cv) + ij] = (i == j)
                ? 0.0f
                : fabsf((float)Sv - 2.0f * (float)negsum) * (1.0f / (float)Sv);
        }
    }
}

extern "C" void kernel_launch(void* const* d_in, const int* in_sizes, int n_in,
                              void* d_out, int out_size, void* d_ws, size_t ws_size,
                              hipStream_t stream) {
    const float* x = (const float*)d_in[0];            // [B, C, S] fp32
    char* ws = (char*)d_ws;
    unsigned int* u      = (unsigned int*)ws;                       // 8 MB phases
    unsigned int* part   = (unsigned int*)(ws + (8u << 20));        // 1.13 MB partials
    unsigned int* flags1 = (unsigned int*)(ws + (16u << 20));       // 512 u32
    unsigned int* flags2 = (unsigned int*)(ws + (16u << 20) + 4096);
    float* out = (float*)d_out;                        // [B, C, C] fp32

    hipLaunchKernelGGL(pli_one, dim3(Bv * Cv / 2), dim3(256), 0, stream,
                       x, u, part, flags1, flags2, out);
}

// Round 4
// 98.143 us; speedup vs baseline: 1.8260x; 1.2215x over previous
//
#include <hip/hip_runtime.h>

#define Bv 16
#define Cv 64
#define Sv 2048
#define NSEG 32           // pli sample-groups per batch (64 samples each)
#define SSEG 64           // samples per pli group
#define ROWS 68           // pli LDS row stride in words (64 ch + 4 pad)
#define NTILE 144         // triangle tiles: dq in 0..8 x qi in 0..15
#define MAGICF 0x4F1BBCDCu   // flag value; workspace poison-fill resets flags each iter

// Forward DIF butterfly: u' = u+v ; v' = (u-v)*w
__device__ __forceinline__ void bf_f(float2& u, float2& v, const float2 w) {
    const float dr = u.x - v.x, di = u.y - v.y;
    u.x += v.x; u.y += v.y;
    v.x = dr * w.x - di * w.y;
    v.y = dr * w.y + di * w.x;
}
// Inverse DIT butterfly: v' = v*conj(w) ; u' = u+v' ; l' = u-v'
__device__ __forceinline__ void bf_i(float2& u, float2& v, const float2 w) {
    const float vr = v.x * w.x + v.y * w.y;
    const float vi = v.y * w.x - v.x * w.y;
    v.x = u.x - vr; v.y = u.y - vi;
    u.x += vr; u.y += vi;
}
__device__ __forceinline__ float2 csq(const float2 a) {
    return make_float2(a.x * a.x - a.y * a.y, 2.0f * a.x * a.y);
}
__device__ __forceinline__ float2 cm1(const float2 a) {   // a * e^{-i pi/4}
    const float cq = 0.70710678118654752f;
    return make_float2(cq * (a.x + a.y), cq * (a.y - a.x));
}
__device__ __forceinline__ float2 cmi(const float2 a) {   // a * e^{-i pi/2}
    return make_float2(a.y, -a.x);
}
// Bank-conflict-breaking storage map for the FFT scratch: n -> n + n/8.
__device__ __forceinline__ int pad(int n) { return n + (n >> 3); }

// Agent-scope write-through store: completion (vmcnt) => device visibility,
// so a later RELAXED flag store after __syncthreads (which drains vmcnt(0))
// cannot pass it. No wbl2 / release fence needed anywhere.
__device__ __forceinline__ void st_agent(unsigned int* p, unsigned int v) {
    __hip_atomic_store(p, v, __ATOMIC_RELAXED, __HIP_MEMORY_SCOPE_AGENT);
}
__device__ __forceinline__ unsigned int ld_flag(const unsigned int* p) {
    return __hip_atomic_load((unsigned int*)p, __ATOMIC_RELAXED, __HIP_MEMORY_SCOPE_AGENT);
}
// Rendezvous: wave-parallel relaxed poll of the 32 flags of batch b, then an
// acquire fence so subsequent PLAIN (cached) loads see the published data.
__device__ __forceinline__ void wait_batch(const unsigned int* f, int t) {
    if (t < 32) {
        int guard = 0;
        while (ld_flag(&f[t]) != MAGICF && guard < (1 << 20)) {
            ++guard;
            __builtin_amdgcn_s_sleep(2);
        }
    }
    __syncthreads();
    __builtin_amdgcn_fence(__ATOMIC_ACQUIRE, "agent");
}

// ---------------------------------------------------------------------------
// Single kernel, 512 blocks x 256 threads, all resident (2 blocks/CU):
//   phase 0: block blk -> Hilbert for channels 2blk,2blk+1 -> u32 phases
//   rendezvous on batch's 32 flags1
//   phase 1: block (b,g) -> PLI sign counts for 64-sample group g -> partials
//   rendezvous on batch's 32 flags2
//   phase 2: DISTRIBUTED finalize: block (b,g) reduces 128 outputs of batch b
// R3's 68us body was ~50us of tail: 16 finalize blocks x 512 serialized
// uncached atomic loads each (Occupancy 9%, VALUBusy 16%). R4 spreads the
// finalize over all 512 blocks (32 independent cached loads/thread) and
// switches all data reads to plain cached loads behind acquire fences.
// ---------------------------------------------------------------------------
__global__ __launch_bounds__(256, 2) void pli_one(const float* __restrict__ x,
                                                  unsigned int* __restrict__ u,
                                                  unsigned int* __restrict__ part,
                                                  unsigned int* __restrict__ flags1,
                                                  unsigned int* __restrict__ flags2,
                                                  float* __restrict__ out) {
    // Time-shared LDS: FFT scratch (18432 B) / count tile (17408 B)
    __shared__ __align__(16) unsigned char shraw[(Sv + Sv / 8) * sizeof(float2)];
    float2* const zz = (float2*)shraw;
    unsigned int* const uL = (unsigned int*)shraw;
    const int t = threadIdx.x;
    const int blk = blockIdx.x;
    const int b = blk >> 5;          // batch (same for hilbert + count roles)
    const int g = blk & (NSEG - 1);  // sample group for count/finalize roles

    // ===================== phase 0: Hilbert + phase quantize =====================
    {
        const int c0 = blk * 2;
        const float* x0 = x + (size_t)c0 * Sv;
        const float* x1 = x0 + Sv;

        const float PI = 3.14159265358979323846f;
        float2 bA4, bB4, bC2;
        sincosf(-PI * (float)t * (1.0f / 1024.0f), &bA4.y, &bA4.x);
        sincosf(-PI * (float)(t & 31) * (1.0f / 128.0f), &bB4.y, &bB4.x);
        sincosf(-PI * (float)(t & 7) * (1.0f / 16.0f), &bC2.y, &bC2.x);
        const float2 bA2 = csq(bA4), bA1 = csq(bA2);
        const float2 bB2 = csq(bB4), bB1 = csq(bB2);
        const float2 bC1 = csq(bC2);

        float xa[8], xb[8];
        float2 z[8];
        #pragma unroll
        for (int k = 0; k < 8; ++k) {
            xa[k] = x0[t + 256 * k];
            xb[k] = x1[t + 256 * k];
            z[k] = make_float2(xa[k], xb[k]);
        }

        // ---- fwd halves 1024,512,256 (stride 256) ----
        {
            const float2 w1 = cm1(bA4);
            bf_f(z[0], z[4], bA4);      bf_f(z[1], z[5], w1);
            bf_f(z[2], z[6], cmi(bA4)); bf_f(z[3], z[7], cmi(w1));
            const float2 wB = cmi(bA2);
            bf_f(z[0], z[2], bA2); bf_f(z[1], z[3], wB);
            bf_f(z[4], z[6], bA2); bf_f(z[5], z[7], wB);
            bf_f(z[0], z[1], bA1); bf_f(z[2], z[3], bA1);
            bf_f(z[4], z[5], bA1); bf_f(z[6], z[7], bA1);
        }
        #pragma unroll
        for (int k = 0; k < 8; ++k) zz[pad(t + 256 * k)] = z[k];
        __syncthreads();

        // ---- fwd halves 128,64,32 (stride 32) ----
        {
            const int r = t & 31, base = (t >> 5) * 256 + r;
            #pragma unroll
            for (int k = 0; k < 8; ++k) z[k] = zz[pad(base + 32 * k)];
            const float2 w1 = cm1(bB4);
            bf_f(z[0], z[4], bB4);      bf_f(z[1], z[5], w1);
            bf_f(z[2], z[6], cmi(bB4)); bf_f(z[3], z[7], cmi(w1));
            const float2 wB = cmi(bB2);
            bf_f(z[0], z[2], bB2); bf_f(z[1], z[3], wB);
            bf_f(z[4], z[6], bB2); bf_f(z[5], z[7], wB);
            bf_f(z[0], z[1], bB1); bf_f(z[2], z[3], bB1);
            bf_f(z[4], z[5], bB1); bf_f(z[6], z[7], bB1);
            #pragma unroll
            for (int k = 0; k < 8; ++k) zz[pad(base + 32 * k)] = z[k];
        }
        __syncthreads();

        // ---- fwd halves 16,8 (stride 8; two 4-sets) ----
        {
            const int r = t & 7, base0 = (t >> 3) * 32 + r, base1 = base0 + 1024;
            #pragma unroll
            for (int k = 0; k < 4; ++k) {
                z[k] = zz[pad(base0 + 8 * k)];
                z[4 + k] = zz[pad(base1 + 8 * k)];
            }
            const float2 wB = cmi(bC2);
            bf_f(z[0], z[2], bC2); bf_f(z[1], z[3], wB);
            bf_f(z[4], z[6], bC2); bf_f(z[5], z[7], wB);
            bf_f(z[0], z[1], bC1); bf_f(z[2], z[3], bC1);
            bf_f(z[4], z[5], bC1); bf_f(z[6], z[7], bC1);
            #pragma unroll
            for (int k = 0; k < 4; ++k) {
                zz[pad(base0 + 8 * k)] = z[k];
                zz[pad(base1 + 8 * k)] = z[4 + k];
            }
        }
        __syncthreads();

        // ---- fused: fwd 4,2,1 ; Hilbert filter * 1/N ; inv 1,2,4 ----
        {
            const int base = 8 * t;
            #pragma unroll
            for (int k = 0; k < 8; ++k) z[k] = zz[pad(base + k)];
            const float cq = 0.70710678118654752f;
            const float2 W1  = make_float2(1.0f, 0.0f);
            const float2 W41 = make_float2(cq, -cq);
            const float2 W42 = make_float2(0.0f, -1.0f);
            const float2 W43 = make_float2(-cq, -cq);
            bf_f(z[0], z[4], W1);  bf_f(z[1], z[5], W41);
            bf_f(z[2], z[6], W42); bf_f(z[3], z[7], W43);
            bf_f(z[0], z[2], W1); bf_f(z[1], z[3], W42);
            bf_f(z[4], z[6], W1); bf_f(z[5], z[7], W42);
            bf_f(z[0], z[1], W1); bf_f(z[2], z[3], W1);
            bf_f(z[4], z[5], W1); bf_f(z[6], z[7], W1);
            const float inv = 1.0f / (float)Sv;
            #pragma unroll
            for (int k = 0; k < 8; ++k) {
                const int kk = (int)(__brev((unsigned)(base + k)) >> 21);   // logical index!
                const float m = (kk == 0 || kk == Sv / 2) ? inv : (kk < Sv / 2 ? 2.0f * inv : 0.0f);
                z[k].x *= m; z[k].y *= m;
            }
            bf_i(z[0], z[1], W1); bf_i(z[2], z[3], W1);
            bf_i(z[4], z[5], W1); bf_i(z[6], z[7], W1);
            bf_i(z[0], z[2], W1); bf_i(z[1], z[3], W42);
            bf_i(z[4], z[6], W1); bf_i(z[5], z[7], W42);
            bf_i(z[0], z[4], W1);  bf_i(z[1], z[5], W41);
            bf_i(z[2], z[6], W42); bf_i(z[3], z[7], W43);
            #pragma unroll
            for (int k = 0; k < 8; ++k) zz[pad(base + k)] = z[k];
        }
        __syncthreads();

        // ---- inv halves 8,16 (stride 8; two 4-sets) ----
        {
            const int r = t & 7, base0 = (t >> 3) * 32 + r, base1 = base0 + 1024;
            #pragma unroll
            for (int k = 0; k < 4; ++k) {
                z[k] = zz[pad(base0 + 8 * k)];
                z[4 + k] = zz[pad(base1 + 8 * k)];
            }
            bf_i(z[0], z[1], bC1); bf_i(z[2], z[3], bC1);
            bf_i(z[4], z[5], bC1); bf_i(z[6], z[7], bC1);
            const float2 wB = cmi(bC2);
            bf_i(z[0], z[2], bC2); bf_i(z[1], z[3], wB);
            bf_i(z[4], z[6], bC2); bf_i(z[5], z[7], wB);
            #pragma unroll
            for (int k = 0; k < 4; ++k) {
                zz[pad(base0 + 8 * k)] = z[k];
                zz[pad(base1 + 8 * k)] = z[4 + k];
            }
        }
        __syncthreads();

        // ---- inv halves 32,64,128 (stride 32) ----
        {
            const int r = t & 31, base = (t >> 5) * 256 + r;
            #pragma unroll
            for (int k = 0; k < 8; ++k) z[k] = zz[pad(base + 32 * k)];
            bf_i(z[0], z[1], bB1); bf_i(z[2], z[3], bB1);
            bf_i(z[4], z[5], bB1); bf_i(z[6], z[7], bB1);
            const float2 wB = cmi(bB2);
            bf_i(z[0], z[2], bB2); bf_i(z[1], z[3], wB);
            bf_i(z[4], z[6], bB2); bf_i(z[5], z[7], wB);
            const float2 w1 = cm1(bB4);
            bf_i(z[0], z[4], bB4);      bf_i(z[1], z[5], w1);
            bf_i(z[2], z[6], cmi(bB4)); bf_i(z[3], z[7], cmi(w1));
            #pragma unroll
            for (int k = 0; k < 8; ++k) zz[pad(base + 32 * k)] = z[k];
        }
        __syncthreads();

        // ---- inv halves 256,512,1024 (stride 256) + phase-quantize (agent st) ----
        {
            #pragma unroll
            for (int k = 0; k < 8; ++k) z[k] = zz[pad(t + 256 * k)];
            bf_i(z[0], z[1], bA1); bf_i(z[2], z[3], bA1);
            bf_i(z[4], z[5], bA1); bf_i(z[6], z[7], bA1);
            const float2 wB = cmi(bA2);
            bf_i(z[0], z[2], bA2); bf_i(z[1], z[3], wB);
            bf_i(z[4], z[6], bA2); bf_i(z[5], z[7], wB);
            const float2 w1 = cm1(bA4);
            bf_i(z[0], z[4], bA4);      bf_i(z[1], z[5], w1);
            bf_i(z[2], z[6], cmi(bA4)); bf_i(z[3], z[7], cmi(w1));
            unsigned int* u0 = u + (size_t)c0 * Sv;
            unsigned int* u1 = u0 + Sv;
            const float SC = 683565275.576f;   // 2^31 / pi ; mod 2^32 == mod 2*pi
            #pragma unroll
            for (int k = 0; k < 8; ++k) {
                const int n = t + 256 * k;
                const float ha = z[k].y - xb[k];   // H(x_a) = Im(w) - x_b
                const float hb = xa[k] - z[k].x;   // H(x_b) = x_a - Re(w)
                st_agent(&u0[n], (unsigned int)__float2int_rz(atan2f(ha, xa[k]) * SC));
                st_agent(&u1[n], (unsigned int)__float2int_rz(atan2f(hb, xb[k]) * SC));
            }
        }
    }

    // Publish phase 0: syncthreads drained vmcnt(0) for every wave, and all u
    // stores were agent-scope write-through => relaxed flag store suffices.
    __syncthreads();
    if (t == 0) st_agent(&flags1[blk], MAGICF);

    wait_batch(flags1 + b * 32, t);

    // ===================== phase 1: PLI negative-sign counts =====================
    {
        const unsigned int* ub = u + (size_t)b * Cv * Sv + g * SSEG;

        #pragma unroll
        for (int it = 0; it < 16; ++it) {
            const int e = t + 256 * it;
            const int ch = e >> 6;
            const int s = e & (SSEG - 1);
            uL[s * ROWS + ch] = ub[(size_t)ch * Sv + s];   // plain cached load
        }
        __syncthreads();

        if (t < NTILE) {
            const int qi = t & 15;
            const int dq = t >> 4;                  // 0..8
            const int i0 = qi * 4;
            const int j0 = ((qi + dq) & 15) * 4;
            int neg[4][4] = {};

            #pragma unroll 4
            for (int s = 0; s < SSEG; ++s) {
                const uint4 ui = *(const uint4*)&uL[s * ROWS + i0];
                const uint4 uj = *(const uint4*)&uL[s * ROWS + j0];
                const unsigned int uia[4] = {ui.x, ui.y, ui.z, ui.w};
                const unsigned int uja[4] = {uj.x, uj.y, uj.z, uj.w};
                #pragma unroll
                for (int a = 0; a < 4; ++a) {
                    #pragma unroll
                    for (int c = 0; c < 4; ++c) {
                        // wrapped phase diff negative <=> top bit of (uia-uja)
                        neg[a][c] += (int)((uia[a] - uja[c]) >> 31);
                    }
                }
            }

            unsigned int* Pb = part + ((size_t)blk * NTILE + t) * 4;
            #pragma unroll
            for (int a = 0; a < 4; ++a) {
                const unsigned int pk = (unsigned)neg[a][0] | ((unsigned)neg[a][1] << 8)
                                      | ((unsigned)neg[a][2] << 16) | ((unsigned)neg[a][3] << 24);
                st_agent(&Pb[a], pk);
            }
        }
    }

    __syncthreads();
    if (t == 0) st_agent(&flags2[blk], MAGICF);

    wait_batch(flags2 + b * 32, t);

    // ============ phase 2: distributed finalize (128 outputs per block) ============
    if (t < 128) {
        const unsigned int* pw = part + (size_t)b * (NSEG * NTILE * 4);
        const int ij = g * 128 + t;                // 4096 outputs of batch b
        const int i = ij >> 6, j = ij & 63;
        const int qi = i >> 2, a = i & 3;
        const int qj = j >> 2, c = j & 3;
        const int gg = (qj - qi) & 15;
        int tile, wsel, bsel;
        if (gg <= 8) { tile = gg * 16 + qi;        wsel = a; bsel = c; }
        else         { tile = (16 - gg) * 16 + qj; wsel = c; bsel = a; }
        const unsigned int* pp = pw + tile * 4 + wsel;
        const int sh = 8 * bsel;
        int negsum = 0;
        #pragma unroll
        for (int s = 0; s < NSEG; ++s)             // 32 independent cached loads
            negsum += (int)((pp[s * (NTILE * 4)] >> sh) & 255u);
        out[b * (Cv * Cv) + ij] = (i == j)
            ? 0.0f
            : fabsf((float)Sv - 2.0f * (float)negsum) * (1.0f / (float)Sv);
    }
}

extern "C" void kernel_launch(void* const* d_in, const int* in_sizes, int n_in,
                              void* d_out, int out_size, void* d_ws, size_t ws_size,
                              hipStream_t stream) {
    const float* x = (const float*)d_in[0];            // [B, C, S] fp32
    char* ws = (char*)d_ws;
    unsigned int* u      = (unsigned int*)ws;                       // 8 MB phases
    unsigned int* part   = (unsigned int*)(ws + (8u << 20));        // 1.13 MB partials
    unsigned int* flags1 = (unsigned int*)(ws + (16u << 20));       // 512 u32
    unsigned int* flags2 = (unsigned int*)(ws + (16u << 20) + 4096);
    float* out = (float*)d_out;                        // [B, C, C] fp32

    hipLaunchKernelGGL(pli_one, dim3(Bv * Cv / 2), dim3(256), 0, stream,
                       x, u, part, flags1, flags2, out);
}

// Round 5
// 81.377 us; speedup vs baseline: 2.2022x; 1.2060x over previous
//
#include <hip/hip_runtime.h>

#define Bv 16
#define Cv 64
#define Sv 2048
#define NSEG 32           // pli sample-groups per batch (64 samples each)
#define SSEG 64           // samples per pli group
#define ROWS 68           // pli LDS row stride in words (64 ch + 4 pad)
#define NTILE 144         // triangle tiles: dq in 0..8 x qi in 0..15
#define MAGICF 0x4F1BBCDCu   // flag value; workspace poison-fill resets flags each iter

// Forward DIF butterfly: u' = u+v ; v' = (u-v)*w
__device__ __forceinline__ void bf_f(float2& u, float2& v, const float2 w) {
    const float dr = u.x - v.x, di = u.y - v.y;
    u.x += v.x; u.y += v.y;
    v.x = dr * w.x - di * w.y;
    v.y = dr * w.y + di * w.x;
}
// Inverse DIT butterfly: v' = v*conj(w) ; u' = u+v' ; l' = u-v'
__device__ __forceinline__ void bf_i(float2& u, float2& v, const float2 w) {
    const float vr = v.x * w.x + v.y * w.y;
    const float vi = v.y * w.x - v.x * w.y;
    v.x = u.x - vr; v.y = u.y - vi;
    u.x += vr; u.y += vi;
}
__device__ __forceinline__ float2 csq(const float2 a) {
    return make_float2(a.x * a.x - a.y * a.y, 2.0f * a.x * a.y);
}
__device__ __forceinline__ float2 cm1(const float2 a) {   // a * e^{-i pi/4}
    const float cq = 0.70710678118654752f;
    return make_float2(cq * (a.x + a.y), cq * (a.y - a.x));
}
__device__ __forceinline__ float2 cmi(const float2 a) {   // a * e^{-i pi/2}
    return make_float2(a.y, -a.x);
}
// Bank-conflict-breaking storage map for the FFT scratch: n -> n + n/8.
__device__ __forceinline__ int pad(int n) { return n + (n >> 3); }

// Agent-scope accessors. ALL cross-block data (u, part, flags) is written
// with write-through agent stores and read with uncached agent loads, so no
// L2 coherence is ever needed -> NO acquire fences (R4's two per-rendezvous
// agent acquire fences compiled to whole-L2 invalidates; 1024 of them per
// kernel instance trashed every co-resident block's cache: FETCH +4MB and
// ~30us of diffuse stall).
__device__ __forceinline__ void st_agent(unsigned int* p, unsigned int v) {
    __hip_atomic_store(p, v, __ATOMIC_RELAXED, __HIP_MEMORY_SCOPE_AGENT);
}
__device__ __forceinline__ unsigned int ld_agent(const unsigned int* p) {
    return __hip_atomic_load((unsigned int*)p, __ATOMIC_RELAXED, __HIP_MEMORY_SCOPE_AGENT);
}
// Rendezvous: wave-parallel relaxed poll of the 32 flags of batch b. No fence.
__device__ __forceinline__ void wait_batch(const unsigned int* f, int t) {
    if (t < 32) {
        int guard = 0;
        while (ld_agent(&f[t]) != MAGICF && guard < (1 << 20)) {
            ++guard;
            __builtin_amdgcn_s_sleep(2);
        }
    }
    __syncthreads();
}

// ---------------------------------------------------------------------------
// Single kernel, 512 blocks x 256 threads, all resident (2 blocks/CU):
//   phase 0: block blk -> Hilbert for channels 2blk,2blk+1 -> u32 phases
//   rendezvous on batch's 32 flags1 (no fence)
//   phase 1: block (b,g) -> PLI sign counts for group g (uncached u reads)
//   rendezvous on batch's 32 flags2 (no fence)
//   phase 2: distributed finalize, uncached partial reads
// ---------------------------------------------------------------------------
__global__ __launch_bounds__(256, 2) void pli_one(const float* __restrict__ x,
                                                  unsigned int* __restrict__ u,
                                                  unsigned int* __restrict__ part,
                                                  unsigned int* __restrict__ flags1,
                                                  unsigned int* __restrict__ flags2,
                                                  float* __restrict__ out) {
    // Time-shared LDS: FFT scratch (18432 B) / count tile (17408 B)
    __shared__ __align__(16) unsigned char shraw[(Sv + Sv / 8) * sizeof(float2)];
    float2* const zz = (float2*)shraw;
    unsigned int* const uL = (unsigned int*)shraw;
    const int t = threadIdx.x;
    const int blk = blockIdx.x;
    const int b = blk >> 5;          // batch (same for hilbert + count roles)
    const int g = blk & (NSEG - 1);  // sample group for count/finalize roles

    // ===================== phase 0: Hilbert + phase quantize =====================
    {
        const int c0 = blk * 2;
        const float* x0 = x + (size_t)c0 * Sv;
        const float* x1 = x0 + Sv;

        const float PI = 3.14159265358979323846f;
        float2 bA4, bB4, bC2;
        sincosf(-PI * (float)t * (1.0f / 1024.0f), &bA4.y, &bA4.x);
        sincosf(-PI * (float)(t & 31) * (1.0f / 128.0f), &bB4.y, &bB4.x);
        sincosf(-PI * (float)(t & 7) * (1.0f / 16.0f), &bC2.y, &bC2.x);
        const float2 bA2 = csq(bA4), bA1 = csq(bA2);
        const float2 bB2 = csq(bB4), bB1 = csq(bB2);
        const float2 bC1 = csq(bC2);

        float xa[8], xb[8];
        float2 z[8];
        #pragma unroll
        for (int k = 0; k < 8; ++k) {
            xa[k] = x0[t + 256 * k];
            xb[k] = x1[t + 256 * k];
            z[k] = make_float2(xa[k], xb[k]);
        }

        // ---- fwd halves 1024,512,256 (stride 256) ----
        {
            const float2 w1 = cm1(bA4);
            bf_f(z[0], z[4], bA4);      bf_f(z[1], z[5], w1);
            bf_f(z[2], z[6], cmi(bA4)); bf_f(z[3], z[7], cmi(w1));
            const float2 wB = cmi(bA2);
            bf_f(z[0], z[2], bA2); bf_f(z[1], z[3], wB);
            bf_f(z[4], z[6], bA2); bf_f(z[5], z[7], wB);
            bf_f(z[0], z[1], bA1); bf_f(z[2], z[3], bA1);
            bf_f(z[4], z[5], bA1); bf_f(z[6], z[7], bA1);
        }
        #pragma unroll
        for (int k = 0; k < 8; ++k) zz[pad(t + 256 * k)] = z[k];
        __syncthreads();

        // ---- fwd halves 128,64,32 (stride 32) ----
        {
            const int r = t & 31, base = (t >> 5) * 256 + r;
            #pragma unroll
            for (int k = 0; k < 8; ++k) z[k] = zz[pad(base + 32 * k)];
            const float2 w1 = cm1(bB4);
            bf_f(z[0], z[4], bB4);      bf_f(z[1], z[5], w1);
            bf_f(z[2], z[6], cmi(bB4)); bf_f(z[3], z[7], cmi(w1));
            const float2 wB = cmi(bB2);
            bf_f(z[0], z[2], bB2); bf_f(z[1], z[3], wB);
            bf_f(z[4], z[6], bB2); bf_f(z[5], z[7], wB);
            bf_f(z[0], z[1], bB1); bf_f(z[2], z[3], bB1);
            bf_f(z[4], z[5], bB1); bf_f(z[6], z[7], bB1);
            #pragma unroll
            for (int k = 0; k < 8; ++k) zz[pad(base + 32 * k)] = z[k];
        }
        __syncthreads();

        // ---- fwd halves 16,8 (stride 8; two 4-sets) ----
        {
            const int r = t & 7, base0 = (t >> 3) * 32 + r, base1 = base0 + 1024;
            #pragma unroll
            for (int k = 0; k < 4; ++k) {
                z[k] = zz[pad(base0 + 8 * k)];
                z[4 + k] = zz[pad(base1 + 8 * k)];
            }
            const float2 wB = cmi(bC2);
            bf_f(z[0], z[2], bC2); bf_f(z[1], z[3], wB);
            bf_f(z[4], z[6], bC2); bf_f(z[5], z[7], wB);
            bf_f(z[0], z[1], bC1); bf_f(z[2], z[3], bC1);
            bf_f(z[4], z[5], bC1); bf_f(z[6], z[7], bC1);
            #pragma unroll
            for (int k = 0; k < 4; ++k) {
                zz[pad(base0 + 8 * k)] = z[k];
                zz[pad(base1 + 8 * k)] = z[4 + k];
            }
        }
        __syncthreads();

        // ---- fused: fwd 4,2,1 ; Hilbert filter * 1/N ; inv 1,2,4 ----
        {
            const int base = 8 * t;
            #pragma unroll
            for (int k = 0; k < 8; ++k) z[k] = zz[pad(base + k)];
            const float cq = 0.70710678118654752f;
            const float2 W1  = make_float2(1.0f, 0.0f);
            const float2 W41 = make_float2(cq, -cq);
            const float2 W42 = make_float2(0.0f, -1.0f);
            const float2 W43 = make_float2(-cq, -cq);
            bf_f(z[0], z[4], W1);  bf_f(z[1], z[5], W41);
            bf_f(z[2], z[6], W42); bf_f(z[3], z[7], W43);
            bf_f(z[0], z[2], W1); bf_f(z[1], z[3], W42);
            bf_f(z[4], z[6], W1); bf_f(z[5], z[7], W42);
            bf_f(z[0], z[1], W1); bf_f(z[2], z[3], W1);
            bf_f(z[4], z[5], W1); bf_f(z[6], z[7], W1);
            const float inv = 1.0f / (float)Sv;
            #pragma unroll
            for (int k = 0; k < 8; ++k) {
                const int kk = (int)(__brev((unsigned)(base + k)) >> 21);   // logical index!
                const float m = (kk == 0 || kk == Sv / 2) ? inv : (kk < Sv / 2 ? 2.0f * inv : 0.0f);
                z[k].x *= m; z[k].y *= m;
            }
            bf_i(z[0], z[1], W1); bf_i(z[2], z[3], W1);
            bf_i(z[4], z[5], W1); bf_i(z[6], z[7], W1);
            bf_i(z[0], z[2], W1); bf_i(z[1], z[3], W42);
            bf_i(z[4], z[6], W1); bf_i(z[5], z[7], W42);
            bf_i(z[0], z[4], W1);  bf_i(z[1], z[5], W41);
            bf_i(z[2], z[6], W42); bf_i(z[3], z[7], W43);
            #pragma unroll
            for (int k = 0; k < 8; ++k) zz[pad(base + k)] = z[k];
        }
        __syncthreads();

        // ---- inv halves 8,16 (stride 8; two 4-sets) ----
        {
            const int r = t & 7, base0 = (t >> 3) * 32 + r, base1 = base0 + 1024;
            #pragma unroll
            for (int k = 0; k < 4; ++k) {
                z[k] = zz[pad(base0 + 8 * k)];
                z[4 + k] = zz[pad(base1 + 8 * k)];
            }
            bf_i(z[0], z[1], bC1); bf_i(z[2], z[3], bC1);
            bf_i(z[4], z[5], bC1); bf_i(z[6], z[7], bC1);
            const float2 wB = cmi(bC2);
            bf_i(z[0], z[2], bC2); bf_i(z[1], z[3], wB);
            bf_i(z[4], z[6], bC2); bf_i(z[5], z[7], wB);
            #pragma unroll
            for (int k = 0; k < 4; ++k) {
                zz[pad(base0 + 8 * k)] = z[k];
                zz[pad(base1 + 8 * k)] = z[4 + k];
            }
        }
        __syncthreads();

        // ---- inv halves 32,64,128 (stride 32) ----
        {
            const int r = t & 31, base = (t >> 5) * 256 + r;
            #pragma unroll
            for (int k = 0; k < 8; ++k) z[k] = zz[pad(base + 32 * k)];
            bf_i(z[0], z[1], bB1); bf_i(z[2], z[3], bB1);
            bf_i(z[4], z[5], bB1); bf_i(z[6], z[7], bB1);
            const float2 wB = cmi(bB2);
            bf_i(z[0], z[2], bB2); bf_i(z[1], z[3], wB);
            bf_i(z[4], z[6], bB2); bf_i(z[5], z[7], wB);
            const float2 w1 = cm1(bB4);
            bf_i(z[0], z[4], bB4);      bf_i(z[1], z[5], w1);
            bf_i(z[2], z[6], cmi(bB4)); bf_i(z[3], z[7], cmi(w1));
            #pragma unroll
            for (int k = 0; k < 8; ++k) zz[pad(base + 32 * k)] = z[k];
        }
        __syncthreads();

        // ---- inv halves 256,512,1024 (stride 256) + phase-quantize (agent st) ----
        {
            #pragma unroll
            for (int k = 0; k < 8; ++k) z[k] = zz[pad(t + 256 * k)];
            bf_i(z[0], z[1], bA1); bf_i(z[2], z[3], bA1);
            bf_i(z[4], z[5], bA1); bf_i(z[6], z[7], bA1);
            const float2 wB = cmi(bA2);
            bf_i(z[0], z[2], bA2); bf_i(z[1], z[3], wB);
            bf_i(z[4], z[6], bA2); bf_i(z[5], z[7], wB);
            const float2 w1 = cm1(bA4);
            bf_i(z[0], z[4], bA4);      bf_i(z[1], z[5], w1);
            bf_i(z[2], z[6], cmi(bA4)); bf_i(z[3], z[7], cmi(w1));
            unsigned int* u0 = u + (size_t)c0 * Sv;
            unsigned int* u1 = u0 + Sv;
            const float SC = 683565275.576f;   // 2^31 / pi ; mod 2^32 == mod 2*pi
            #pragma unroll
            for (int k = 0; k < 8; ++k) {
                const int n = t + 256 * k;
                const float ha = z[k].y - xb[k];   // H(x_a) = Im(w) - x_b
                const float hb = xa[k] - z[k].x;   // H(x_b) = x_a - Re(w)
                st_agent(&u0[n], (unsigned int)__float2int_rz(atan2f(ha, xa[k]) * SC));
                st_agent(&u1[n], (unsigned int)__float2int_rz(atan2f(hb, xb[k]) * SC));
            }
        }
    }

    // Publish phase 0: syncthreads drained vmcnt(0) for every wave, and all u
    // stores were agent-scope write-through => relaxed flag store suffices.
    __syncthreads();
    if (t == 0) st_agent(&flags1[blk], MAGICF);

    wait_batch(flags1 + b * 32, t);

    // ===================== phase 1: PLI negative-sign counts =====================
    {
        const unsigned int* ub = u + (size_t)b * Cv * Sv + g * SSEG;

        #pragma unroll
        for (int it = 0; it < 16; ++it) {
            const int e = t + 256 * it;
            const int ch = e >> 6;
            const int s = e & (SSEG - 1);
            uL[s * ROWS + ch] = ld_agent(&ub[(size_t)ch * Sv + s]);   // uncached, 16 indep
        }
        __syncthreads();

        if (t < NTILE) {
            const int qi = t & 15;
            const int dq = t >> 4;                  // 0..8
            const int i0 = qi * 4;
            const int j0 = ((qi + dq) & 15) * 4;
            int neg[4][4] = {};

            #pragma unroll 4
            for (int s = 0; s < SSEG; ++s) {
                const uint4 ui = *(const uint4*)&uL[s * ROWS + i0];
                const uint4 uj = *(const uint4*)&uL[s * ROWS + j0];
                const unsigned int uia[4] = {ui.x, ui.y, ui.z, ui.w};
                const unsigned int uja[4] = {uj.x, uj.y, uj.z, uj.w};
                #pragma unroll
                for (int a = 0; a < 4; ++a) {
                    #pragma unroll
                    for (int c = 0; c < 4; ++c) {
                        // wrapped phase diff negative <=> top bit of (uia-uja)
                        neg[a][c] += (int)((uia[a] - uja[c]) >> 31);
                    }
                }
            }

            unsigned int* Pb = part + ((size_t)blk * NTILE + t) * 4;
            #pragma unroll
            for (int a = 0; a < 4; ++a) {
                const unsigned int pk = (unsigned)neg[a][0] | ((unsigned)neg[a][1] << 8)
                                      | ((unsigned)neg[a][2] << 16) | ((unsigned)neg[a][3] << 24);
                st_agent(&Pb[a], pk);
            }
        }
    }

    __syncthreads();
    if (t == 0) st_agent(&flags2[blk], MAGICF);

    wait_batch(flags2 + b * 32, t);

    // ============ phase 2: distributed finalize (128 outputs per block) ============
    if (t < 128) {
        const unsigned int* pw = part + (size_t)b * (NSEG * NTILE * 4);
        const int ij = g * 128 + t;                // 4096 outputs of batch b
        const int i = ij >> 6, j = ij & 63;
        const int qi = i >> 2, a = i & 3;
        const int qj = j >> 2, c = j & 3;
        const int gg = (qj - qi) & 15;
        int tile, wsel, bsel;
        if (gg <= 8) { tile = gg * 16 + qi;        wsel = a; bsel = c; }
        else         { tile = (16 - gg) * 16 + qj; wsel = c; bsel = a; }
        const unsigned int* pp = pw + tile * 4 + wsel;
        const int sh = 8 * bsel;
        int negsum = 0;
        #pragma unroll
        for (int s = 0; s < NSEG; ++s)             // 32 independent uncached loads
            negsum += (int)((ld_agent(&pp[s * (NTILE * 4)]) >> sh) & 255u);
        out[b * (Cv * Cv) + ij] = (i == j)
            ? 0.0f
            : fabsf((float)Sv - 2.0f * (float)negsum) * (1.0f / (float)Sv);
    }
}

extern "C" void kernel_launch(void* const* d_in, const int* in_sizes, int n_in,
                              void* d_out, int out_size, void* d_ws, size_t ws_size,
                              hipStream_t stream) {
    const float* x = (const float*)d_in[0];            // [B, C, S] fp32
    char* ws = (char*)d_ws;
    unsigned int* u      = (unsigned int*)ws;                       // 8 MB phases
    unsigned int* part   = (unsigned int*)(ws + (8u << 20));        // 1.13 MB partials
    unsigned int* flags1 = (unsigned int*)(ws + (16u << 20));       // 512 u32
    unsigned int* flags2 = (unsigned int*)(ws + (16u << 20) + 4096);
    float* out = (float*)d_out;                        // [B, C, C] fp32

    hipLaunchKernelGGL(pli_one, dim3(Bv * Cv / 2), dim3(256), 0, stream,
                       x, u, part, flags1, flags2, out);
}

// Round 6
// 76.291 us; speedup vs baseline: 2.3490x; 1.0667x over previous
//
#include <hip/hip_runtime.h>

#define Bv 16
#define Cv 64
#define Sv 2048
#define NSEG 32           // pli sample-groups per batch (64 samples each)
#define SSEG 64           // samples per pli group
#define ROWS 68           // pli LDS row stride in words (64 ch + 4 pad)
#define NTILE 144         // triangle tiles: dq in 0..8 x qi in 0..15
#define MAGICF 0x4F1BBCDCu   // flag value; workspace poison-fill resets flags each iter

// Forward DIF butterfly: u' = u+v ; v' = (u-v)*w
__device__ __forceinline__ void bf_f(float2& u, float2& v, const float2 w) {
    const float dr = u.x - v.x, di = u.y - v.y;
    u.x += v.x; u.y += v.y;
    v.x = dr * w.x - di * w.y;
    v.y = dr * w.y + di * w.x;
}
// Inverse DIT butterfly: v' = v*conj(w) ; u' = u+v' ; l' = u-v'
__device__ __forceinline__ void bf_i(float2& u, float2& v, const float2 w) {
    const float vr = v.x * w.x + v.y * w.y;
    const float vi = v.y * w.x - v.x * w.y;
    v.x = u.x - vr; v.y = u.y - vi;
    u.x += vr; u.y += vi;
}
__device__ __forceinline__ float2 csq(const float2 a) {
    return make_float2(a.x * a.x - a.y * a.y, 2.0f * a.x * a.y);
}
__device__ __forceinline__ float2 cm1(const float2 a) {   // a * e^{-i pi/4}
    const float cq = 0.70710678118654752f;
    return make_float2(cq * (a.x + a.y), cq * (a.y - a.x));
}
__device__ __forceinline__ float2 cmi(const float2 a) {   // a * e^{-i pi/2}
    return make_float2(a.y, -a.x);
}
// Bank-conflict-breaking storage map for the FFT scratch: n -> n + n/8.
__device__ __forceinline__ int pad(int n) { return n + (n >> 3); }

// Exact-antipodal pseudoangle (replaces atan2f, ~9 ops vs ~70).
// Monotone circle map theta -> u32 with u(theta+pi) == u(theta) + 2^31 EXACTLY:
//   p = h * rcp(|x|+|h|)  (p' = -p exact under (x,h)->(-x,-h): fp sign flip)
//   i = trunc(p * 2^30)   (trunc is odd-symmetric: i' = -i exact)
//   u = x>=0 ?  i  :  2^31 - i   (integer subtract exact => u' = u + 2^31)
// Any monotone antipode-preserving map keeps the half-plane classification
// sign(sin(ti - tj)) <=> ((ui-uj) mod 2^32) >= 2^31 identical to true angles.
// Boundary error ~2^-22 rad (rcp ULP) — same class as atan2f's own error.
__device__ __forceinline__ unsigned int pang(const float x, const float h) {
    const float p = h * __builtin_amdgcn_rcpf(fabsf(x) + fabsf(h));
    const int i = (int)(p * 1073741824.0f);   // p * 2^30, |p| <= 1+eps
    return (x >= 0.0f) ? (unsigned int)i : 0x80000000u - (unsigned int)i;
}

// Agent-scope accessors. ALL cross-block data (u, part, flags) is written
// with write-through agent stores and read with uncached agent loads, so no
// L2 coherence is ever needed -> NO acquire fences (R4 lesson: each agent
// acquire fence is a whole-L2 invalidate; 1024 of them cost ~17us + 4MB
// of refetch).
__device__ __forceinline__ void st_agent(unsigned int* p, unsigned int v) {
    __hip_atomic_store(p, v, __ATOMIC_RELAXED, __HIP_MEMORY_SCOPE_AGENT);
}
__device__ __forceinline__ unsigned int ld_agent(const unsigned int* p) {
    return __hip_atomic_load((unsigned int*)p, __ATOMIC_RELAXED, __HIP_MEMORY_SCOPE_AGENT);
}
// Rendezvous: wave-parallel relaxed poll of the 32 flags of batch b. No fence.
__device__ __forceinline__ void wait_batch(const unsigned int* f, int t) {
    if (t < 32) {
        int guard = 0;
        while (ld_agent(&f[t]) != MAGICF && guard < (1 << 20)) {
            ++guard;
            __builtin_amdgcn_s_sleep(2);
        }
    }
    __syncthreads();
}

// ---------------------------------------------------------------------------
// Single kernel, 512 blocks x 256 threads, all resident (2 blocks/CU):
//   phase 0: block blk -> Hilbert for channels 2blk,2blk+1 -> u32 pseudoangles
//   rendezvous on batch's 32 flags1 (no fence)
//   phase 1: block (b,g) -> PLI sign counts for group g (uncached u reads)
//   rendezvous on batch's 32 flags2 (no fence)
//   phase 2: distributed finalize, uncached partial reads
// ---------------------------------------------------------------------------
__global__ __launch_bounds__(256, 2) void pli_one(const float* __restrict__ x,
                                                  unsigned int* __restrict__ u,
                                                  unsigned int* __restrict__ part,
                                                  unsigned int* __restrict__ flags1,
                                                  unsigned int* __restrict__ flags2,
                                                  float* __restrict__ out) {
    // Time-shared LDS: FFT scratch (18432 B) / count tile (17408 B)
    __shared__ __align__(16) unsigned char shraw[(Sv + Sv / 8) * sizeof(float2)];
    float2* const zz = (float2*)shraw;
    unsigned int* const uL = (unsigned int*)shraw;
    const int t = threadIdx.x;
    const int blk = blockIdx.x;
    const int b = blk >> 5;          // batch (same for hilbert + count roles)
    const int g = blk & (NSEG - 1);  // sample group for count/finalize roles

    // ===================== phase 0: Hilbert + pseudoangle quantize =====================
    {
        const int c0 = blk * 2;
        const float* x0 = x + (size_t)c0 * Sv;
        const float* x1 = x0 + Sv;

        const float PI = 3.14159265358979323846f;
        float2 bA4, bB4, bC2;
        sincosf(-PI * (float)t * (1.0f / 1024.0f), &bA4.y, &bA4.x);
        sincosf(-PI * (float)(t & 31) * (1.0f / 128.0f), &bB4.y, &bB4.x);
        sincosf(-PI * (float)(t & 7) * (1.0f / 16.0f), &bC2.y, &bC2.x);
        const float2 bA2 = csq(bA4), bA1 = csq(bA2);
        const float2 bB2 = csq(bB4), bB1 = csq(bB2);
        const float2 bC1 = csq(bC2);

        float xa[8], xb[8];
        float2 z[8];
        #pragma unroll
        for (int k = 0; k < 8; ++k) {
            xa[k] = x0[t + 256 * k];
            xb[k] = x1[t + 256 * k];
            z[k] = make_float2(xa[k], xb[k]);
        }

        // ---- fwd halves 1024,512,256 (stride 256) ----
        {
            const float2 w1 = cm1(bA4);
            bf_f(z[0], z[4], bA4);      bf_f(z[1], z[5], w1);
            bf_f(z[2], z[6], cmi(bA4)); bf_f(z[3], z[7], cmi(w1));
            const float2 wB = cmi(bA2);
            bf_f(z[0], z[2], bA2); bf_f(z[1], z[3], wB);
            bf_f(z[4], z[6], bA2); bf_f(z[5], z[7], wB);
            bf_f(z[0], z[1], bA1); bf_f(z[2], z[3], bA1);
            bf_f(z[4], z[5], bA1); bf_f(z[6], z[7], bA1);
        }
        #pragma unroll
        for (int k = 0; k < 8; ++k) zz[pad(t + 256 * k)] = z[k];
        __syncthreads();

        // ---- fwd halves 128,64,32 (stride 32) ----
        {
            const int r = t & 31, base = (t >> 5) * 256 + r;
            #pragma unroll
            for (int k = 0; k < 8; ++k) z[k] = zz[pad(base + 32 * k)];
            const float2 w1 = cm1(bB4);
            bf_f(z[0], z[4], bB4);      bf_f(z[1], z[5], w1);
            bf_f(z[2], z[6], cmi(bB4)); bf_f(z[3], z[7], cmi(w1));
            const float2 wB = cmi(bB2);
            bf_f(z[0], z[2], bB2); bf_f(z[1], z[3], wB);
            bf_f(z[4], z[6], bB2); bf_f(z[5], z[7], wB);
            bf_f(z[0], z[1], bB1); bf_f(z[2], z[3], bB1);
            bf_f(z[4], z[5], bB1); bf_f(z[6], z[7], bB1);
            #pragma unroll
            for (int k = 0; k < 8; ++k) zz[pad(base + 32 * k)] = z[k];
        }
        __syncthreads();

        // ---- fwd halves 16,8 (stride 8; two 4-sets) ----
        {
            const int r = t & 7, base0 = (t >> 3) * 32 + r, base1 = base0 + 1024;
            #pragma unroll
            for (int k = 0; k < 4; ++k) {
                z[k] = zz[pad(base0 + 8 * k)];
                z[4 + k] = zz[pad(base1 + 8 * k)];
            }
            const float2 wB = cmi(bC2);
            bf_f(z[0], z[2], bC2); bf_f(z[1], z[3], wB);
            bf_f(z[4], z[6], bC2); bf_f(z[5], z[7], wB);
            bf_f(z[0], z[1], bC1); bf_f(z[2], z[3], bC1);
            bf_f(z[4], z[5], bC1); bf_f(z[6], z[7], bC1);
            #pragma unroll
            for (int k = 0; k < 4; ++k) {
                zz[pad(base0 + 8 * k)] = z[k];
                zz[pad(base1 + 8 * k)] = z[4 + k];
            }
        }
        __syncthreads();

        // ---- fused: fwd 4,2,1 ; Hilbert filter * 1/N ; inv 1,2,4 ----
        {
            const int base = 8 * t;
            #pragma unroll
            for (int k = 0; k < 8; ++k) z[k] = zz[pad(base + k)];
            const float cq = 0.70710678118654752f;
            const float2 W1  = make_float2(1.0f, 0.0f);
            const float2 W41 = make_float2(cq, -cq);
            const float2 W42 = make_float2(0.0f, -1.0f);
            const float2 W43 = make_float2(-cq, -cq);
            bf_f(z[0], z[4], W1);  bf_f(z[1], z[5], W41);
            bf_f(z[2], z[6], W42); bf_f(z[3], z[7], W43);
            bf_f(z[0], z[2], W1); bf_f(z[1], z[3], W42);
            bf_f(z[4], z[6], W1); bf_f(z[5], z[7], W42);
            bf_f(z[0], z[1], W1); bf_f(z[2], z[3], W1);
            bf_f(z[4], z[5], W1); bf_f(z[6], z[7], W1);
            const float inv = 1.0f / (float)Sv;
            #pragma unroll
            for (int k = 0; k < 8; ++k) {
                const int kk = (int)(__brev((unsigned)(base + k)) >> 21);   // logical index!
                const float m = (kk == 0 || kk == Sv / 2) ? inv : (kk < Sv / 2 ? 2.0f * inv : 0.0f);
                z[k].x *= m; z[k].y *= m;
            }
            bf_i(z[0], z[1], W1); bf_i(z[2], z[3], W1);
            bf_i(z[4], z[5], W1); bf_i(z[6], z[7], W1);
            bf_i(z[0], z[2], W1); bf_i(z[1], z[3], W42);
            bf_i(z[4], z[6], W1); bf_i(z[5], z[7], W42);
            bf_i(z[0], z[4], W1);  bf_i(z[1], z[5], W41);
            bf_i(z[2], z[6], W42); bf_i(z[3], z[7], W43);
            #pragma unroll
            for (int k = 0; k < 8; ++k) zz[pad(base + k)] = z[k];
        }
        __syncthreads();

        // ---- inv halves 8,16 (stride 8; two 4-sets) ----
        {
            const int r = t & 7, base0 = (t >> 3) * 32 + r, base1 = base0 + 1024;
            #pragma unroll
            for (int k = 0; k < 4; ++k) {
                z[k] = zz[pad(base0 + 8 * k)];
                z[4 + k] = zz[pad(base1 + 8 * k)];
            }
            bf_i(z[0], z[1], bC1); bf_i(z[2], z[3], bC1);
            bf_i(z[4], z[5], bC1); bf_i(z[6], z[7], bC1);
            const float2 wB = cmi(bC2);
            bf_i(z[0], z[2], bC2); bf_i(z[1], z[3], wB);
            bf_i(z[4], z[6], bC2); bf_i(z[5], z[7], wB);
            #pragma unroll
            for (int k = 0; k < 4; ++k) {
                zz[pad(base0 + 8 * k)] = z[k];
                zz[pad(base1 + 8 * k)] = z[4 + k];
            }
        }
        __syncthreads();

        // ---- inv halves 32,64,128 (stride 32) ----
        {
            const int r = t & 31, base = (t >> 5) * 256 + r;
            #pragma unroll
            for (int k = 0; k < 8; ++k) z[k] = zz[pad(base + 32 * k)];
            bf_i(z[0], z[1], bB1); bf_i(z[2], z[3], bB1);
            bf_i(z[4], z[5], bB1); bf_i(z[6], z[7], bB1);
            const float2 wB = cmi(bB2);
            bf_i(z[0], z[2], bB2); bf_i(z[1], z[3], wB);
            bf_i(z[4], z[6], bB2); bf_i(z[5], z[7], wB);
            const float2 w1 = cm1(bB4);
            bf_i(z[0], z[4], bB4);      bf_i(z[1], z[5], w1);
            bf_i(z[2], z[6], cmi(bB4)); bf_i(z[3], z[7], cmi(w1));
            #pragma unroll
            for (int k = 0; k < 8; ++k) zz[pad(base + 32 * k)] = z[k];
        }
        __syncthreads();

        // ---- inv halves 256,512,1024 (stride 256) + pseudoangle write (agent st) ----
        {
            #pragma unroll
            for (int k = 0; k < 8; ++k) z[k] = zz[pad(t + 256 * k)];
            bf_i(z[0], z[1], bA1); bf_i(z[2], z[3], bA1);
            bf_i(z[4], z[5], bA1); bf_i(z[6], z[7], bA1);
            const float2 wB = cmi(bA2);
            bf_i(z[0], z[2], bA2); bf_i(z[1], z[3], wB);
            bf_i(z[4], z[6], bA2); bf_i(z[5], z[7], wB);
            const float2 w1 = cm1(bA4);
            bf_i(z[0], z[4], bA4);      bf_i(z[1], z[5], w1);
            bf_i(z[2], z[6], cmi(bA4)); bf_i(z[3], z[7], cmi(w1));
            unsigned int* u0 = u + (size_t)c0 * Sv;
            unsigned int* u1 = u0 + Sv;
            #pragma unroll
            for (int k = 0; k < 8; ++k) {
                const int n = t + 256 * k;
                const float ha = z[k].y - xb[k];   // H(x_a) = Im(w) - x_b
                const float hb = xa[k] - z[k].x;   // H(x_b) = x_a - Re(w)
                st_agent(&u0[n], pang(xa[k], ha));
                st_agent(&u1[n], pang(xb[k], hb));
            }
        }
    }

    // Publish phase 0: syncthreads drained vmcnt(0) for every wave, and all u
    // stores were agent-scope write-through => relaxed flag store suffices.
    __syncthreads();
    if (t == 0) st_agent(&flags1[blk], MAGICF);

    wait_batch(flags1 + b * 32, t);

    // ===================== phase 1: PLI negative-sign counts =====================
    {
        const unsigned int* ub = u + (size_t)b * Cv * Sv + g * SSEG;

        // Issue all 16 independent uncached loads first (one latency round),
        // then drain into LDS.
        unsigned int rstage[16];
        #pragma unroll
        for (int it = 0; it < 16; ++it) {
            const int e = t + 256 * it;
            rstage[it] = ld_agent(&ub[(size_t)(e >> 6) * Sv + (e & (SSEG - 1))]);
        }
        #pragma unroll
        for (int it = 0; it < 16; ++it) {
            const int e = t + 256 * it;
            uL[(e & (SSEG - 1)) * ROWS + (e >> 6)] = rstage[it];
        }
        __syncthreads();

        if (t < NTILE) {
            const int qi = t & 15;
            const int dq = t >> 4;                  // 0..8
            const int i0 = qi * 4;
            const int j0 = ((qi + dq) & 15) * 4;
            int neg[4][4] = {};

            #pragma unroll 4
            for (int s = 0; s < SSEG; ++s) {
                const uint4 ui = *(const uint4*)&uL[s * ROWS + i0];
                const uint4 uj = *(const uint4*)&uL[s * ROWS + j0];
                const unsigned int uia[4] = {ui.x, ui.y, ui.z, ui.w};
                const unsigned int uja[4] = {uj.x, uj.y, uj.z, uj.w};
                #pragma unroll
                for (int a = 0; a < 4; ++a) {
                    #pragma unroll
                    for (int c = 0; c < 4; ++c) {
                        // wrapped phase diff negative <=> top bit of (uia-uja)
                        neg[a][c] += (int)((uia[a] - uja[c]) >> 31);
                    }
                }
            }

            unsigned int* Pb = part + ((size_t)blk * NTILE + t) * 4;
            #pragma unroll
            for (int a = 0; a < 4; ++a) {
                const unsigned int pk = (unsigned)neg[a][0] | ((unsigned)neg[a][1] << 8)
                                      | ((unsigned)neg[a][2] << 16) | ((unsigned)neg[a][3] << 24);
                st_agent(&Pb[a], pk);
            }
        }
    }

    __syncthreads();
    if (t == 0) st_agent(&flags2[blk], MAGICF);

    wait_batch(flags2 + b * 32, t);

    // ============ phase 2: distributed finalize (128 outputs per block) ============
    if (t < 128) {
        const unsigned int* pw = part + (size_t)b * (NSEG * NTILE * 4);
        const int ij = g * 128 + t;                // 4096 outputs of batch b
        const int i = ij >> 6, j = ij & 63;
        const int qi = i >> 2, a = i & 3;
        const int qj = j >> 2, c = j & 3;
        const int gg = (qj - qi) & 15;
        int tile, wsel, bsel;
        if (gg <= 8) { tile = gg * 16 + qi;        wsel = a; bsel = c; }
        else         { tile = (16 - gg) * 16 + qj; wsel = c; bsel = a; }
        const unsigned int* pp = pw + tile * 4 + wsel;
        const int sh = 8 * bsel;
        int negsum = 0;
        #pragma unroll
        for (int s = 0; s < NSEG; ++s)             // 32 independent uncached loads
            negsum += (int)((ld_agent(&pp[s * (NTILE * 4)]) >> sh) & 255u);
        out[b * (Cv * Cv) + ij] = (i == j)
            ? 0.0f
            : fabsf((float)Sv - 2.0f * (float)negsum) * (1.0f / (float)Sv);
    }
}

extern "C" void kernel_launch(void* const* d_in, const int* in_sizes, int n_in,
                              void* d_out, int out_size, void* d_ws, size_t ws_size,
                              hipStream_t stream) {
    const float* x = (const float*)d_in[0];            // [B, C, S] fp32
    char* ws = (char*)d_ws;
    unsigned int* u      = (unsigned int*)ws;                       // 8 MB phases
    unsigned int* part   = (unsigned int*)(ws + (8u << 20));        // 1.13 MB partials
    unsigned int* flags1 = (unsigned int*)(ws + (16u << 20));       // 512 u32
    unsigned int* flags2 = (unsigned int*)(ws + (16u << 20) + 4096);
    float* out = (float*)d_out;                        // [B, C, C] fp32

    hipLaunchKernelGGL(pli_one, dim3(Bv * Cv / 2), dim3(256), 0, stream,
                       x, u, part, flags1, flags2, out);
}